// Round 5
// baseline (199.312 us; speedup 1.0000x reference)
//
#include <hip/hip_runtime.h>
#include <math.h>

// Problem dims
#define NB 64
#define NA 23
#define NT 128
#define ND 256
#define NAE 32
#define NS 6
#define NH 8
#define NDM 288
#define NBA (NB*NA)   // 1472

// Workspace layout (float offsets). Total 5,417,609 floats = 21.7 MB.
#define OFF_PK     0           // PK[j][t] = sum_e pe[t][e]*Wk[e][j]*scale : 256*128
#define OFF_PET    32768       // peT[e][t] : 256*128
#define OFF_WKT    65536       // WkTs[j][e] = Wk[e][j]*scale : 256*256
#define OFF_VWO    131072      // VWo[h][e] : 8*288
#define OFF_QBIAS  133376      // qbias[a][j] = bq[j] + E_var[a].Wq[256:,j] : 23*256
#define OFF_CST    139264      // [0..5]=W_static.Wg1, [6]=b_static.Wg1+bg, [7]=bo.Wg0, [8..15]=bv.WoWg per h
#define OFF_EVV    139280      // evv[a][h] : 23*8
#define OFF_PEM    139464      // peM[h][t] = pe @ VWo : 8*128
#define OFF_AGW    140488      // agw[ba][e<256] : 1472*256
#define OFF_Q      517320      // q[ba][j] : 1472*256
#define OFF_QK     894152      // qk[ba][h][e] : 1472*2048
#define OFF_PES    3908808     // peS[ba][h][t] : 1472*1024
#define OFF_S      5416136     // s[ba] : 1472
#define OFF_CNT    5417608     // int completion counter : 1

#define KDIV  0.07195578415606394f    // ln(10000)/128
#define KSCALE 0.17677669529663687f   // 1/sqrt(32)

// ---------------- K1 setup+agw: 600 blocks ----------------
__global__ __launch_bounds__(256) void setup_kernel(
    const float* __restrict__ Wk, const float* __restrict__ Wq,
    const float* __restrict__ bq, const float* __restrict__ E_var,
    const float* __restrict__ Wv, const float* __restrict__ Wo,
    const float* __restrict__ Wg, const float* __restrict__ bv,
    const float* __restrict__ bo, const float* __restrict__ W_static,
    const float* __restrict__ b_static, const float* __restrict__ bg,
    const float* __restrict__ data, const int* __restrict__ lengths,
    const float* __restrict__ W_embed, const float* __restrict__ b_embed,
    float* __restrict__ ws)
{
    const int blk = blockIdx.x, tid = threadIdx.x;
    if (blk < 128) {
        __shared__ float sm[256];
        const int t = blk;
        const int e = tid, i = e >> 1;
        const float dv = __expf(-(float)i * KDIV);
        const float ang = (float)t * dv;
        const float v = (e & 1) ? cosf(ang) : sinf(ang);
        sm[e] = v;
        ws[OFF_PET + e * NT + t] = v;
        __syncthreads();
        float acc = 0.f;
        #pragma unroll 4
        for (int e2 = 0; e2 < 256; ++e2)
            acc = fmaf(sm[e2], Wk[e2 * ND + tid], acc);
        ws[OFF_PK + tid * NT + t] = acc * KSCALE;
    } else if (blk < 384) {
        const int j = blk - 128;
        ws[OFF_WKT + j * 256 + tid] = Wk[tid * ND + j] * KSCALE;
    } else if (blk < 392) {
        const int h = blk - 384;
        __shared__ float wog[32];
        {
            const int jj = tid >> 3, sub = tid & 7;
            const int j = h * 32 + jj;
            float acc = 0.f;
            const int m0 = sub * 36;
            #pragma unroll 4
            for (int m = m0; m < m0 + 36; ++m)
                acc = fmaf(Wo[j * NDM + m], Wg[m], acc);
            acc += __shfl_down(acc, 4, 8);
            acc += __shfl_down(acc, 2, 8);
            acc += __shfl_down(acc, 1, 8);
            if (sub == 0) wog[jj] = acc;
        }
        __syncthreads();
        for (int e = tid; e < NDM; e += 256) {
            float acc = 0.f;
            #pragma unroll 8
            for (int jj = 0; jj < 32; ++jj)
                acc = fmaf(Wv[e * ND + h * 32 + jj], wog[jj], acc);
            ws[OFF_VWO + h * NDM + e] = acc;
        }
    } else if (blk < 415) {
        const int a = blk - 392;
        float acc = bq[tid];
        #pragma unroll 8
        for (int ee = 0; ee < NAE; ++ee)
            acc = fmaf(E_var[a * NAE + ee], Wq[(256 + ee) * ND + tid], acc);
        ws[OFF_QBIAS + a * ND + tid] = acc;
    } else if (blk == 415) {
        __shared__ float sm[256];
        float acc = 0.f;
        const float* row = Wo + tid * NDM;
        for (int m = 0; m < NDM; ++m) acc = fmaf(row[m], Wg[m], acc);
        sm[tid] = acc;   // WoWg
        __syncthreads();
        const int i = tid >> 5, sub = tid & 31;
        float v = 0.f;
        if (i < 6) { for (int m = sub; m < 256; m += 32) v = fmaf(W_static[i * ND + m], Wg[NDM + m], v); }
        else if (i == 6) { for (int m = sub; m < 256; m += 32) v = fmaf(b_static[m], Wg[NDM + m], v); }
        else { for (int m = sub; m < NDM; m += 32) v = fmaf(bo[m], Wg[m], v); }
        #pragma unroll
        for (int off = 16; off > 0; off >>= 1) v += __shfl_down(v, off, 32);
        if (sub == 0) ws[OFF_CST + i] = (i == 6) ? v + bg[0] : v;
        {
            const int h = i, jj = sub;
            float u = bv[h * 32 + jj] * sm[h * 32 + jj];
            #pragma unroll
            for (int off = 16; off > 0; off >>= 1) u += __shfl_down(u, off, 32);
            if (sub == 0) ws[OFF_CST + 8 + h] = u;
        }
        if (tid == 255) ((int*)(ws + OFF_CNT))[0] = 0;
    } else {
        // agw: 8 ba per block
        const int ba0 = (blk - 416) * 8;
        __shared__ float X[8 * 128];
        if (tid < 128) {
            #pragma unroll
            for (int i = 0; i < 8; ++i)
                X[i * 128 + tid] = data[(ba0 + i) * NT + tid];
        }
        __syncthreads();
        const int e = tid, ii = e >> 1;
        const float dv = __expf(-(float)ii * KDIV);
        const float hd = 0.5f * dv;
        const float ish = 1.f / sinf(hd);
        for (int i = 0; i < 8; ++i) {
            const int ba = ba0 + i, a = ba % NA;
            const int Li = lengths[ba];
            const float We = W_embed[a * ND + e];
            const float be = b_embed[a * ND + e];
            float acc = 0.f;
            #pragma unroll 4
            for (int t = 0; t < Li; ++t)
                acc += fmaxf(fmaf(X[i * 128 + t], We, be), 0.f);
            float r = 0.f;
            if (Li > 0) {
                const float s1 = sinf((float)Li * hd);
                const float a2 = (float)(Li - 1) * hd;
                const float num = (e & 1) ? cosf(a2) : sinf(a2);
                r = (acc + num * s1 * ish) / (float)Li;
            }
            ws[OFF_AGW + ba * 256 + e] = r;
        }
    }
}

// ---------------- K2 q + pem + evv: 373 blocks ----------------
__global__ __launch_bounds__(256) void q_kernel(
    const float* __restrict__ Wq, const float* __restrict__ E_var,
    float* __restrict__ ws)
{
    const int blk = blockIdx.x, tid = threadIdx.x;
    if (blk < 368) {
        const int ba0 = blk * 4;
        __shared__ __align__(16) float agwS[1024];  // [f][4]
        int aa[4];
        #pragma unroll
        for (int i = 0; i < 4; ++i) aa[i] = (ba0 + i) % NA;
        {
            float v0 = ws[OFF_AGW + (ba0 + 0) * 256 + tid];
            float v1 = ws[OFF_AGW + (ba0 + 1) * 256 + tid];
            float v2 = ws[OFF_AGW + (ba0 + 2) * 256 + tid];
            float v3 = ws[OFF_AGW + (ba0 + 3) * 256 + tid];
            *(float4*)&agwS[tid * 4] = make_float4(v0, v1, v2, v3);
        }
        __syncthreads();
        const int j = tid;
        float4 acc = make_float4(ws[OFF_QBIAS + aa[0] * ND + j], ws[OFF_QBIAS + aa[1] * ND + j],
                                 ws[OFF_QBIAS + aa[2] * ND + j], ws[OFF_QBIAS + aa[3] * ND + j]);
        #pragma unroll 8
        for (int f = 0; f < 256; ++f) {
            const float w = Wq[f * ND + j];
            const float4 ag = *(const float4*)&agwS[f * 4];
            acc.x = fmaf(ag.x, w, acc.x); acc.y = fmaf(ag.y, w, acc.y);
            acc.z = fmaf(ag.z, w, acc.z); acc.w = fmaf(ag.w, w, acc.w);
        }
        ws[OFF_Q + (ba0 + 0) * 256 + j] = acc.x;
        ws[OFF_Q + (ba0 + 1) * 256 + j] = acc.y;
        ws[OFF_Q + (ba0 + 2) * 256 + j] = acc.z;
        ws[OFF_Q + (ba0 + 3) * 256 + j] = acc.w;
    } else if (blk < 372) {
        const int h = (blk - 368) * 2 + (tid >> 7);
        const int t = tid & 127;
        float acc = 0.f;
        #pragma unroll 4
        for (int e = 0; e < 256; ++e)
            acc = fmaf(ws[OFF_PET + e * NT + t], ws[OFF_VWO + h * NDM + e], acc);
        ws[OFF_PEM + h * NT + t] = acc;
    } else {
        if (tid < 184) {
            const int a = tid >> 3, h = tid & 7;
            float acc = 0.f;
            #pragma unroll 8
            for (int ee = 0; ee < NAE; ++ee)
                acc = fmaf(E_var[a * NAE + ee], ws[OFF_VWO + h * NDM + 256 + ee], acc);
            ws[OFF_EVV + tid] = acc;
        }
    }
}

// ---------------- K3 qk + peS: 1472 blocks ----------------
__global__ __launch_bounds__(256) void qkps_kernel(float* __restrict__ ws)
{
    const int blk = blockIdx.x, tid = threadIdx.x;
    const bool isPes = blk >= 736;
    const int idx = isPes ? blk - 736 : blk;
    const int h = idx / 92;
    const int ba0 = (idx % 92) * 16;
    __shared__ float qS[512];   // [16 ba][32 j]
    #pragma unroll
    for (int r = 0; r < 2; ++r) {
        const int ii = tid + r * 256;
        const int i = ii >> 5, j = ii & 31;
        qS[ii] = ws[OFF_Q + (ba0 + i) * 256 + h * 32 + j];
    }
    __syncthreads();
    if (!isPes) {
        const int e = tid;
        float acc[16];
        #pragma unroll
        for (int i = 0; i < 16; ++i) acc[i] = 0.f;
        const float* wkp = ws + OFF_WKT + (h * 32) * 256 + e;
        #pragma unroll 4
        for (int j = 0; j < 32; ++j) {
            const float wk = wkp[j * 256];
            #pragma unroll
            for (int i = 0; i < 16; ++i) acc[i] = fmaf(qS[i * 32 + j], wk, acc[i]);
        }
        #pragma unroll
        for (int i = 0; i < 16; ++i)
            ws[OFF_QK + (size_t)(ba0 + i) * 2048 + h * 256 + e] = acc[i];
    } else {
        const int t = tid & 127, bg = tid >> 7;
        float acc[8];
        #pragma unroll
        for (int i = 0; i < 8; ++i) acc[i] = 0.f;
        const float* pkp = ws + OFF_PK + (h * 32) * 128 + t;
        #pragma unroll 4
        for (int j = 0; j < 32; ++j) {
            const float pk = pkp[j * 128];
            #pragma unroll
            for (int i = 0; i < 8; ++i) acc[i] = fmaf(qS[(bg * 8 + i) * 32 + j], pk, acc[i]);
        }
        #pragma unroll
        for (int i = 0; i < 8; ++i)
            ws[OFF_PES + (size_t)(ba0 + bg * 8 + i) * 1024 + h * 128 + t] = acc[i];
    }
}

// ---------------- K4 ef (+ fused final via atomic ticket): 1472 blocks ----------------
// Register-tiled: 4 t per thread, 8 e-slice groups of 32 lanes.
// LDS delivered bytes/block: 256thr * 32iter * 72B = 590 KB (was 2.36 MB).
__global__ __launch_bounds__(256) void ef_kernel(
    const float* __restrict__ data, const int* __restrict__ lengths,
    const float* __restrict__ W_embed, const float* __restrict__ b_embed,
    const float* __restrict__ statics,
    float* __restrict__ ws, float* __restrict__ out)
{
    const int wg = blockIdx.x, tid = threadIdx.x;
    const int a = wg % NA;
    const int L = lengths[wg];

    __shared__ __align__(16) float combo[4096]; // 4 planes [256 e][float4]; reused as partials + sc/mvb
    __shared__ float xs[128];
    __shared__ float2 Wb[256];
    __shared__ float red[4];
    __shared__ int amLast;

    if (L > 0) {
        if (tid < 128) xs[tid] = data[wg * NT + tid];
        Wb[tid] = make_float2(W_embed[a * ND + tid], b_embed[a * ND + tid]);
        {
            float4* cb4w = (float4*)combo;
            const float* qkp = ws + OFF_QK + (size_t)wg * 2048;
            const float* vw = ws + OFF_VWO;
            cb4w[tid]       = make_float4(qkp[tid], qkp[256 + tid], qkp[512 + tid], qkp[768 + tid]);
            cb4w[256 + tid] = make_float4(qkp[1024 + tid], qkp[1280 + tid], qkp[1536 + tid], qkp[1792 + tid]);
            cb4w[512 + tid] = make_float4(vw[tid], vw[288 + tid], vw[576 + tid], vw[864 + tid]);
            cb4w[768 + tid] = make_float4(vw[1152 + tid], vw[1440 + tid], vw[1728 + tid], vw[2016 + tid]);
        }
        __syncthreads();

        const int w = tid >> 6, l = tid & 63, slot = l & 31;
        const int g = w * 2 + (l >> 5);     // e-slice 0..7
        const int ebase = g * 32;
        const float xt0 = xs[slot], xt1 = xs[slot + 32], xt2 = xs[slot + 64], xt3 = xs[slot + 96];
        float aS[4][8], aM[4][8];
        #pragma unroll
        for (int it = 0; it < 4; ++it)
            #pragma unroll
            for (int k = 0; k < 8; ++k) { aS[it][k] = 0.f; aM[it][k] = 0.f; }

        const float4* cb4 = (const float4*)combo;
        #pragma unroll 2
        for (int ee = 0; ee < 32; ++ee) {
            const int e = ebase + ee;
            const float2 wb = Wb[e];
            const float4 c0 = cb4[e];
            const float4 c1 = cb4[256 + e];
            const float4 c2 = cb4[512 + e];
            const float4 c3 = cb4[768 + e];
            float mm[4];
            mm[0] = fmaxf(fmaf(xt0, wb.x, wb.y), 0.f);
            mm[1] = fmaxf(fmaf(xt1, wb.x, wb.y), 0.f);
            mm[2] = fmaxf(fmaf(xt2, wb.x, wb.y), 0.f);
            mm[3] = fmaxf(fmaf(xt3, wb.x, wb.y), 0.f);
            #pragma unroll
            for (int it = 0; it < 4; ++it) {
                const float m = mm[it];
                aS[it][0] = fmaf(m, c0.x, aS[it][0]); aS[it][1] = fmaf(m, c0.y, aS[it][1]);
                aS[it][2] = fmaf(m, c0.z, aS[it][2]); aS[it][3] = fmaf(m, c0.w, aS[it][3]);
                aS[it][4] = fmaf(m, c1.x, aS[it][4]); aS[it][5] = fmaf(m, c1.y, aS[it][5]);
                aS[it][6] = fmaf(m, c1.z, aS[it][6]); aS[it][7] = fmaf(m, c1.w, aS[it][7]);
                aM[it][0] = fmaf(m, c2.x, aM[it][0]); aM[it][1] = fmaf(m, c2.y, aM[it][1]);
                aM[it][2] = fmaf(m, c2.z, aM[it][2]); aM[it][3] = fmaf(m, c2.w, aM[it][3]);
                aM[it][4] = fmaf(m, c3.x, aM[it][4]); aM[it][5] = fmaf(m, c3.y, aM[it][5]);
                aM[it][6] = fmaf(m, c3.z, aM[it][6]); aM[it][7] = fmaf(m, c3.w, aM[it][7]);
            }
        }

        // merge the two half-wave e-slices in-register (lanes l and l^32 share t-set)
        #pragma unroll
        for (int it = 0; it < 4; ++it)
            #pragma unroll
            for (int k = 0; k < 8; ++k) {
                aS[it][k] += __shfl_xor(aS[it][k], 32, 64);
                aM[it][k] += __shfl_xor(aM[it][k], 32, 64);
            }
        __syncthreads();   // all combo reads done -> reuse region as partial buffer

        float4* Pq = (float4*)combo;
        const bool lo = (l < 32);
        if (w >= 2 && lo) {
            const int base = (w - 2) * 512;
            #pragma unroll
            for (int it = 0; it < 4; ++it) {
                Pq[base + (it * 4 + 0) * 32 + slot] = make_float4(aS[it][0], aS[it][1], aS[it][2], aS[it][3]);
                Pq[base + (it * 4 + 1) * 32 + slot] = make_float4(aS[it][4], aS[it][5], aS[it][6], aS[it][7]);
                Pq[base + (it * 4 + 2) * 32 + slot] = make_float4(aM[it][0], aM[it][1], aM[it][2], aM[it][3]);
                Pq[base + (it * 4 + 3) * 32 + slot] = make_float4(aM[it][4], aM[it][5], aM[it][6], aM[it][7]);
            }
        }
        __syncthreads();
        if (w < 2 && lo) {
            const int base = w * 512;
            #pragma unroll
            for (int it = 0; it < 4; ++it) {
                const float4 p0 = Pq[base + (it * 4 + 0) * 32 + slot];
                const float4 p1 = Pq[base + (it * 4 + 1) * 32 + slot];
                const float4 p2 = Pq[base + (it * 4 + 2) * 32 + slot];
                const float4 p3 = Pq[base + (it * 4 + 3) * 32 + slot];
                aS[it][0] += p0.x; aS[it][1] += p0.y; aS[it][2] += p0.z; aS[it][3] += p0.w;
                aS[it][4] += p1.x; aS[it][5] += p1.y; aS[it][6] += p1.z; aS[it][7] += p1.w;
                aM[it][0] += p2.x; aM[it][1] += p2.y; aM[it][2] += p2.z; aM[it][3] += p2.w;
                aM[it][4] += p3.x; aM[it][5] += p3.y; aM[it][6] += p3.z; aM[it][7] += p3.w;
            }
        }
        __syncthreads();
        if (w == 1 && lo) {
            #pragma unroll
            for (int it = 0; it < 4; ++it) {
                Pq[(it * 4 + 0) * 32 + slot] = make_float4(aS[it][0], aS[it][1], aS[it][2], aS[it][3]);
                Pq[(it * 4 + 1) * 32 + slot] = make_float4(aS[it][4], aS[it][5], aS[it][6], aS[it][7]);
                Pq[(it * 4 + 2) * 32 + slot] = make_float4(aM[it][0], aM[it][1], aM[it][2], aM[it][3]);
                Pq[(it * 4 + 3) * 32 + slot] = make_float4(aM[it][4], aM[it][5], aM[it][6], aM[it][7]);
            }
        }
        __syncthreads();
        if (w == 0 && lo) {
            const float* pes = ws + OFF_PES + (size_t)wg * 1024;
            const float* pem = ws + OFF_PEM;
            float* sc  = combo + 2048;
            float* mvb = combo + 3072;
            #pragma unroll
            for (int it = 0; it < 4; ++it) {
                const float4 p0 = Pq[(it * 4 + 0) * 32 + slot];
                const float4 p1 = Pq[(it * 4 + 1) * 32 + slot];
                const float4 p2 = Pq[(it * 4 + 2) * 32 + slot];
                const float4 p3 = Pq[(it * 4 + 3) * 32 + slot];
                aS[it][0] += p0.x; aS[it][1] += p0.y; aS[it][2] += p0.z; aS[it][3] += p0.w;
                aS[it][4] += p1.x; aS[it][5] += p1.y; aS[it][6] += p1.z; aS[it][7] += p1.w;
                aM[it][0] += p2.x; aM[it][1] += p2.y; aM[it][2] += p2.z; aM[it][3] += p2.w;
                aM[it][4] += p3.x; aM[it][5] += p3.y; aM[it][6] += p3.z; aM[it][7] += p3.w;
                const int t = slot + 32 * it;
                #pragma unroll
                for (int h = 0; h < 8; ++h) {
                    sc[h * 128 + t]  = aS[it][h] + pes[h * 128 + t];
                    mvb[h * 128 + t] = aM[it][h] + pem[h * 128 + t];
                }
            }
        }
        __syncthreads();

        // per-head softmax over t<L; s_h = sum_t p*(mv+vb)
        {
            const float* sc  = combo + 2048;
            const float* mvb = combo + 3072;
            const int wv = tid >> 6, lane = tid & 63;
            float wsum = 0.f;
            for (int hh = 0; hh < 2; ++hh) {
                const int h = wv * 2 + hh;
                float s1 = (lane < L) ? sc[h * 128 + lane] : -3e38f;
                float s2 = (lane + 64 < L) ? sc[h * 128 + 64 + lane] : -3e38f;
                float mx = fmaxf(s1, s2);
                #pragma unroll
                for (int off = 32; off > 0; off >>= 1)
                    mx = fmaxf(mx, __shfl_down(mx, off, 64));
                mx = __shfl(mx, 0, 64);
                const float vbv = ws[OFF_EVV + a * 8 + h] + ws[OFF_CST + 8 + h];
                float e1 = (lane < L) ? __expf(s1 - mx) : 0.f;
                float e2 = (lane + 64 < L) ? __expf(s2 - mx) : 0.f;
                float num = e1 * (mvb[h * 128 + lane] + vbv);
                num = fmaf(e2, mvb[h * 128 + 64 + lane] + vbv, num);
                float den = e1 + e2;
                #pragma unroll
                for (int off = 32; off > 0; off >>= 1) {
                    num += __shfl_down(num, off, 64);
                    den += __shfl_down(den, off, 64);
                }
                if (lane == 0) wsum += num / den;
            }
            if (lane == 0) red[wv] = wsum;
        }
        __syncthreads();
    }

    if (tid == 0) {
        const float sval = (L > 0) ? (ws[OFF_CST + 7] + red[0] + red[1] + red[2] + red[3]) : 0.f;
        ws[OFF_S + wg] = sval;
        __threadfence();
        const int prev = atomicAdd((int*)(ws + OFF_CNT), 1);
        amLast = (prev == NBA - 1);
    }
    __syncthreads();
    if (amLast) {
        __threadfence();
        if (tid < NB) {
            const int b = tid;
            const float* s_arr = ws + OFF_S;
            const float* cst = ws + OFF_CST;
            float sum = 0.f;
            int n = 0;
            for (int aa = 0; aa < NA; ++aa) {
                if (lengths[b * NA + aa] > 0) { sum += s_arr[b * NA + aa]; ++n; }
            }
            float o = sum / ((float)n + 1e-9f);
            #pragma unroll
            for (int i = 0; i < NS; ++i)
                o = fmaf(statics[b * NS + i], cst[i], o);
            o += cst[6];
            out[b] = o;
        }
    }
}

extern "C" void kernel_launch(void* const* d_in, const int* in_sizes, int n_in,
                              void* d_out, int out_size, void* d_ws, size_t ws_size,
                              hipStream_t stream) {
    const float* data     = (const float*)d_in[0];
    // d_in[1] = time (implied by mask; unused)
    const int*   mask     = (const int*)d_in[2];
    const float* statics  = (const float*)d_in[3];
    const float* W_embed  = (const float*)d_in[4];
    const float* b_embed  = (const float*)d_in[5];
    const float* E_var    = (const float*)d_in[6];
    const float* W_static = (const float*)d_in[7];
    const float* b_static = (const float*)d_in[8];
    const float* Wq       = (const float*)d_in[9];
    const float* bq       = (const float*)d_in[10];
    const float* Wk       = (const float*)d_in[11];
    // d_in[12] = bk (uniform over t -> cancels in softmax; unused)
    const float* Wv       = (const float*)d_in[13];
    const float* bv       = (const float*)d_in[14];
    const float* Wo       = (const float*)d_in[15];
    const float* bo       = (const float*)d_in[16];
    const float* Wg       = (const float*)d_in[17];
    const float* bg       = (const float*)d_in[18];
    float* out = (float*)d_out;
    float* ws  = (float*)d_ws;

    setup_kernel<<<dim3(600), dim3(256), 0, stream>>>(Wk, Wq, bq, E_var, Wv, Wo, Wg,
                                                      bv, bo, W_static, b_static, bg,
                                                      data, mask, W_embed, b_embed, ws);
    q_kernel<<<dim3(373), dim3(256), 0, stream>>>(Wq, E_var, ws);
    qkps_kernel<<<dim3(1472), dim3(256), 0, stream>>>(ws);
    ef_kernel<<<dim3(NBA), dim3(256), 0, stream>>>(data, mask, W_embed, b_embed,
                                                   statics, ws, out);
}

// Round 7
// 190.905 us; speedup vs baseline: 1.0440x; 1.0440x over previous
//
#include <hip/hip_runtime.h>
#include <math.h>

// Problem dims
#define NB 64
#define NA 23
#define NT 128
#define ND 256
#define NAE 32
#define NS 6
#define NH 8
#define NDM 288
#define NBA (NB*NA)   // 1472

// Workspace layout (float offsets). Total 4,665,993 floats = 18.7 MB.
// All float4-loaded regions are 4-float aligned.
#define OFF_PK     0           // PK[j][t] : 256*128
#define OFF_PET    32768       // peT[e][t] : 256*128
#define OFF_WKT    65536       // WkTs[j][e] = Wk[e][j]*scale : 256*256
#define OFF_VWO    131072      // VWo[h][e] : 8*288 (for evv + pem)
#define OFF_VWOP   133376      // VWoP[e][h] : 256*8 (plane layout for ef)
#define OFF_QBIAS  135424      // qbias[a][j] : 23*256
#define OFF_CST    141312      // 16 consts
#define OFF_EVV    141328      // evv[a][h] : 23*8
#define OFF_PEMT   141512      // pemT[t][h] : 128*8
#define OFF_QK     142536      // qkP[ba][e][h] : 1472*2048
#define OFF_PES    3157192     // pesT[ba][t][h] : 1472*1024
#define OFF_S      4664520     // s[ba] : 1472
#define OFF_CNT    4665992     // int completion counter

#define KDIV  0.07195578415606394f    // ln(10000)/128
#define KSCALE 0.17677669529663687f   // 1/sqrt(32)

// ---------------- K1 setup: 416 blocks ----------------
//  [0,128)   : pe row t=blk (1 transcendental/thread) -> peT + PK
//  [128,384) : WkTs transpose rows
//  [384,392) : per-head VWo (+ VWoP plane copy)
//  [392,415) : qbias[a][:]
//  [415]     : cst[0..15] + zero CNT
__global__ __launch_bounds__(256) void setup_kernel(
    const float* __restrict__ Wk, const float* __restrict__ Wq,
    const float* __restrict__ bq, const float* __restrict__ E_var,
    const float* __restrict__ Wv, const float* __restrict__ Wo,
    const float* __restrict__ Wg, const float* __restrict__ bv,
    const float* __restrict__ bo, const float* __restrict__ W_static,
    const float* __restrict__ b_static, const float* __restrict__ bg,
    float* __restrict__ ws)
{
    const int blk = blockIdx.x, tid = threadIdx.x;
    if (blk < 128) {
        __shared__ float sm[256];
        const int t = blk;
        const int e = tid, i = e >> 1;
        const float dv = __expf(-(float)i * KDIV);
        const float ang = (float)t * dv;
        const float v = (e & 1) ? cosf(ang) : sinf(ang);
        sm[e] = v;
        ws[OFF_PET + e * NT + t] = v;
        __syncthreads();
        float acc = 0.f;
        #pragma unroll 4
        for (int e2 = 0; e2 < 256; ++e2)
            acc = fmaf(sm[e2], Wk[e2 * ND + tid], acc);
        ws[OFF_PK + tid * NT + t] = acc * KSCALE;
    } else if (blk < 384) {
        const int j = blk - 128;
        ws[OFF_WKT + j * 256 + tid] = Wk[tid * ND + j] * KSCALE;
    } else if (blk < 392) {
        const int h = blk - 384;
        __shared__ float wog[32];
        {
            const int jj = tid >> 3, sub = tid & 7;
            const int j = h * 32 + jj;
            float acc = 0.f;
            const int m0 = sub * 36;
            #pragma unroll 4
            for (int m = m0; m < m0 + 36; ++m)
                acc = fmaf(Wo[j * NDM + m], Wg[m], acc);
            acc += __shfl_down(acc, 4, 8);
            acc += __shfl_down(acc, 2, 8);
            acc += __shfl_down(acc, 1, 8);
            if (sub == 0) wog[jj] = acc;
        }
        __syncthreads();
        for (int e = tid; e < NDM; e += 256) {
            float acc = 0.f;
            #pragma unroll 8
            for (int jj = 0; jj < 32; ++jj)
                acc = fmaf(Wv[e * ND + h * 32 + jj], wog[jj], acc);
            ws[OFF_VWO + h * NDM + e] = acc;
            if (e < 256) ws[OFF_VWOP + e * 8 + h] = acc;
        }
    } else if (blk < 415) {
        const int a = blk - 392;
        float acc = bq[tid];
        #pragma unroll 8
        for (int ee = 0; ee < NAE; ++ee)
            acc = fmaf(E_var[a * NAE + ee], Wq[(256 + ee) * ND + tid], acc);
        ws[OFF_QBIAS + a * ND + tid] = acc;
    } else {
        __shared__ float sm[256];
        float acc = 0.f;
        const float* row = Wo + tid * NDM;
        for (int m = 0; m < NDM; ++m) acc = fmaf(row[m], Wg[m], acc);
        sm[tid] = acc;   // WoWg
        __syncthreads();
        const int i = tid >> 5, sub = tid & 31;
        float v = 0.f;
        if (i < 6) { for (int m = sub; m < 256; m += 32) v = fmaf(W_static[i * ND + m], Wg[NDM + m], v); }
        else if (i == 6) { for (int m = sub; m < 256; m += 32) v = fmaf(b_static[m], Wg[NDM + m], v); }
        else { for (int m = sub; m < NDM; m += 32) v = fmaf(bo[m], Wg[m], v); }
        #pragma unroll
        for (int off = 16; off > 0; off >>= 1) v += __shfl_down(v, off, 32);
        if (sub == 0) ws[OFF_CST + i] = (i == 6) ? v + bg[0] : v;
        {
            const int h = i, jj = sub;
            float u = bv[h * 32 + jj] * sm[h * 32 + jj];
            #pragma unroll
            for (int off = 16; off > 0; off >>= 1) u += __shfl_down(u, off, 32);
            if (sub == 0) ws[OFF_CST + 8 + h] = u;
        }
        if (tid == 255) ((int*)(ws + OFF_CNT))[0] = 0;
    }
}

// ---------------- K2 prod: 741 blocks ----------------
//  [0,736)   : 2 ba per block — agw -> q -> qk (plane layout) -> peS (t<L only)
//  [736,740) : pemT[t][h] (2 h per block)
//  [740]     : evv[a][h]
__global__ __launch_bounds__(256) void prod_kernel(
    const float* __restrict__ data, const int* __restrict__ lengths,
    const float* __restrict__ W_embed, const float* __restrict__ b_embed,
    const float* __restrict__ E_var, const float* __restrict__ Wq,
    float* __restrict__ ws)
{
    const int blk = blockIdx.x, tid = threadIdx.x;
    if (blk < 736) {
        const int ba0 = blk * 2;
        const int a0 = ba0 % NA, a1 = (ba0 + 1) % NA;
        const int L0 = lengths[ba0], L1 = lengths[ba0 + 1];
        __shared__ float X[2 * 128];
        __shared__ float agwS[2 * 256];
        __shared__ float qS[2 * 256];
        if (tid < 128) {
            X[tid]       = data[ba0 * NT + tid];
            X[128 + tid] = data[(ba0 + 1) * NT + tid];
        }
        __syncthreads();
        // agw (relu sum over t<L + closed-form pe cumsum) / L
        {
            const int e = tid, ii = e >> 1;
            const float dv = __expf(-(float)ii * KDIV);
            const float hd = 0.5f * dv;
            const float ish = 1.f / sinf(hd);
            #pragma unroll
            for (int i = 0; i < 2; ++i) {
                const int a = i ? a1 : a0;
                const int Li = i ? L1 : L0;
                const float We = W_embed[a * ND + e];
                const float be = b_embed[a * ND + e];
                float acc = 0.f;
                #pragma unroll 4
                for (int t = 0; t < Li; ++t)
                    acc += fmaxf(fmaf(X[i * 128 + t], We, be), 0.f);
                float r = 0.f;
                if (Li > 0) {
                    const float s1 = sinf((float)Li * hd);
                    const float a2 = (float)(Li - 1) * hd;
                    const float num = (e & 1) ? cosf(a2) : sinf(a2);
                    r = (acc + num * s1 * ish) / (float)Li;
                }
                agwS[i * 256 + e] = r;
            }
        }
        __syncthreads();
        // q for both ba (Wq read once, used twice)
        {
            const int j = tid;
            float acc0 = ws[OFF_QBIAS + a0 * ND + j];
            float acc1 = ws[OFF_QBIAS + a1 * ND + j];
            #pragma unroll 8
            for (int f = 0; f < 256; ++f) {
                const float w = Wq[f * ND + j];
                acc0 = fmaf(agwS[f], w, acc0);
                acc1 = fmaf(agwS[256 + f], w, acc1);
            }
            qS[j] = acc0;
            qS[256 + j] = acc1;
        }
        __syncthreads();
        // qk: thread e, all 8 heads, both ba; write plane layout [ba][e][8]
        {
            const int e = tid;
            float q0[8], q1[8];
            for (int h = 0; h < 8; ++h) {
                float acc0 = 0.f, acc1 = 0.f;
                const float* wkp = ws + OFF_WKT + (h * 32) * 256 + e;
                #pragma unroll 8
                for (int j = 0; j < 32; ++j) {
                    const float w = wkp[j * 256];
                    acc0 = fmaf(qS[h * 32 + j], w, acc0);
                    acc1 = fmaf(qS[256 + h * 32 + j], w, acc1);
                }
                q0[h] = acc0; q1[h] = acc1;
            }
            float4* o0 = (float4*)(ws + OFF_QK + (size_t)ba0 * 2048 + e * 8);
            float4* o1 = (float4*)(ws + OFF_QK + (size_t)(ba0 + 1) * 2048 + e * 8);
            o0[0] = make_float4(q0[0], q0[1], q0[2], q0[3]);
            o0[1] = make_float4(q0[4], q0[5], q0[6], q0[7]);
            o1[0] = make_float4(q1[0], q1[1], q1[2], q1[3]);
            o1[1] = make_float4(q1[4], q1[5], q1[6], q1[7]);
        }
        // peS: thread (t, hgroup of 4), both ba; only t < L needed
        {
            const int t = tid & 127, hg = tid >> 7;
            float p0[4], p1[4];
            #pragma unroll
            for (int p = 0; p < 4; ++p) { p0[p] = 0.f; p1[p] = 0.f; }
            #pragma unroll
            for (int p = 0; p < 4; ++p) {
                const int h = hg * 4 + p;
                const float* pkp = ws + OFF_PK + (h * 32) * 128 + t;
                #pragma unroll 4
                for (int j = 0; j < 32; ++j) {
                    const float pk = pkp[j * 128];
                    p0[p] = fmaf(qS[h * 32 + j], pk, p0[p]);
                    p1[p] = fmaf(qS[256 + h * 32 + j], pk, p1[p]);
                }
            }
            if (t < L0)
                ((float4*)(ws + OFF_PES + (size_t)ba0 * 1024 + t * 8))[hg] =
                    make_float4(p0[0], p0[1], p0[2], p0[3]);
            if (t < L1)
                ((float4*)(ws + OFF_PES + (size_t)(ba0 + 1) * 1024 + t * 8))[hg] =
                    make_float4(p1[0], p1[1], p1[2], p1[3]);
        }
    } else if (blk < 740) {
        const int h = (blk - 736) * 2 + (tid >> 7);
        const int t = tid & 127;
        float acc = 0.f;
        #pragma unroll 4
        for (int e = 0; e < 256; ++e)
            acc = fmaf(ws[OFF_PET + e * NT + t], ws[OFF_VWO + h * NDM + e], acc);
        ws[OFF_PEMT + t * 8 + h] = acc;
    } else {
        if (tid < 184) {
            const int a = tid >> 3, h = tid & 7;
            float acc = 0.f;
            #pragma unroll 8
            for (int ee = 0; ee < NAE; ++ee)
                acc = fmaf(E_var[a * NAE + ee], ws[OFF_VWO + h * NDM + 256 + ee], acc);
            ws[OFF_EVV + tid] = acc;
        }
    }
}

// ---------------- K3 ef (+ fused final via atomic ticket): 1472 blocks ----------------
// R4-style broadcast hot loop + L-adaptive wave skip (waves own t-ranges of 64).
__global__ __launch_bounds__(256) void ef_kernel(
    const float* __restrict__ data, const int* __restrict__ lengths,
    const float* __restrict__ W_embed, const float* __restrict__ b_embed,
    const float* __restrict__ statics,
    float* __restrict__ ws, float* __restrict__ out)
{
    const int wg = blockIdx.x, tid = threadIdx.x;
    const int a = wg % NA;
    const int L = lengths[wg];

    __shared__ __align__(16) float combo[4096]; // planes [qk03|qk47|vw03|vw47][e]; reused as sc/mvb/partials
    __shared__ float xs[128];
    __shared__ float2 Wb[256];
    __shared__ float red[4];
    __shared__ int amLast;

    if (L > 0) {
        if (tid < 128) xs[tid] = data[wg * NT + tid];
        Wb[tid] = make_float2(W_embed[a * ND + tid], b_embed[a * ND + tid]);
        {
            float4* cb4w = (float4*)combo;
            const float4* qkp = (const float4*)(ws + OFF_QK + (size_t)wg * 2048);
            const float4* vwp = (const float4*)(ws + OFF_VWOP);
            cb4w[tid]       = qkp[tid * 2];
            cb4w[256 + tid] = qkp[tid * 2 + 1];
            cb4w[512 + tid] = vwp[tid * 2];
            cb4w[768 + tid] = vwp[tid * 2 + 1];
        }
        __syncthreads();

        const int t = tid & 127, half = tid >> 7;
        const int tlo = tid & 64;            // this wave's t-range base (0 or 64)
        const bool act = (L > tlo);          // wave-uniform: skip whole wave when range empty
        float accS[8], accM[8];
        #pragma unroll
        for (int h = 0; h < 8; ++h) { accS[h] = 0.f; accM[h] = 0.f; }
        if (act) {
            const float xt = xs[t];
            const int ebase = half * 128;
            const float4* cb4 = (const float4*)combo;
            #pragma unroll 2
            for (int ee = 0; ee < 128; ++ee) {
                const float2 wb = Wb[ebase + ee];
                const float m = fmaxf(fmaf(xt, wb.x, wb.y), 0.f);
                const float4 c0 = cb4[ebase + ee];
                const float4 c1 = cb4[256 + ebase + ee];
                const float4 c2 = cb4[512 + ebase + ee];
                const float4 c3 = cb4[768 + ebase + ee];
                accS[0] = fmaf(m, c0.x, accS[0]); accS[1] = fmaf(m, c0.y, accS[1]);
                accS[2] = fmaf(m, c0.z, accS[2]); accS[3] = fmaf(m, c0.w, accS[3]);
                accS[4] = fmaf(m, c1.x, accS[4]); accS[5] = fmaf(m, c1.y, accS[5]);
                accS[6] = fmaf(m, c1.z, accS[6]); accS[7] = fmaf(m, c1.w, accS[7]);
                accM[0] = fmaf(m, c2.x, accM[0]); accM[1] = fmaf(m, c2.y, accM[1]);
                accM[2] = fmaf(m, c2.z, accM[2]); accM[3] = fmaf(m, c2.w, accM[3]);
                accM[4] = fmaf(m, c3.x, accM[4]); accM[5] = fmaf(m, c3.y, accM[5]);
                accM[6] = fmaf(m, c3.z, accM[6]); accM[7] = fmaf(m, c3.w, accM[7]);
            }
        }
        __syncthreads();   // all combo reads done -> reuse region
        float* sc  = combo;
        float* mvb = combo + 1024;
        float* scP = combo + 2048;
        float* mvP = combo + 3072;
        if (half == 1 && act) {
            #pragma unroll
            for (int h = 0; h < 8; ++h) { scP[h * 128 + t] = accS[h]; mvP[h * 128 + t] = accM[h]; }
        }
        __syncthreads();
        if (half == 0 && act) {
            const float4* pes = (const float4*)(ws + OFF_PES + (size_t)wg * 1024 + t * 8);
            const float4* pem = (const float4*)(ws + OFF_PEMT + t * 8);
            const float4 ps0 = pes[0], ps1 = pes[1];
            const float4 pm0 = pem[0], pm1 = pem[1];
            const float psA[8] = {ps0.x, ps0.y, ps0.z, ps0.w, ps1.x, ps1.y, ps1.z, ps1.w};
            const float pmA[8] = {pm0.x, pm0.y, pm0.z, pm0.w, pm1.x, pm1.y, pm1.z, pm1.w};
            #pragma unroll
            for (int h = 0; h < 8; ++h) {
                sc[h * 128 + t]  = accS[h] + scP[h * 128 + t] + psA[h];
                mvb[h * 128 + t] = accM[h] + mvP[h * 128 + t] + pmA[h];
            }
        }
        __syncthreads();

        // per-head softmax over t<L; s_h = sum_t p*(mv+vb)
        {
            const int wv = tid >> 6, lane = tid & 63;
            float wsum = 0.f;
            for (int hh = 0; hh < 2; ++hh) {
                const int h = wv * 2 + hh;
                float s1 = (lane < L) ? sc[h * 128 + lane] : -3e38f;
                float s2 = (lane + 64 < L) ? sc[h * 128 + 64 + lane] : -3e38f;
                float mx = fmaxf(s1, s2);
                #pragma unroll
                for (int off = 32; off > 0; off >>= 1)
                    mx = fmaxf(mx, __shfl_down(mx, off, 64));
                mx = __shfl(mx, 0, 64);
                const float vbv = ws[OFF_EVV + a * 8 + h] + ws[OFF_CST + 8 + h];
                float e1 = (lane < L) ? __expf(s1 - mx) : 0.f;
                float e2 = (lane + 64 < L) ? __expf(s2 - mx) : 0.f;
                float num = (lane < L) ? e1 * (mvb[h * 128 + lane] + vbv) : 0.f;
                if (lane + 64 < L) num = fmaf(e2, mvb[h * 128 + 64 + lane] + vbv, num);
                float den = e1 + e2;
                #pragma unroll
                for (int off = 32; off > 0; off >>= 1) {
                    num += __shfl_down(num, off, 64);
                    den += __shfl_down(den, off, 64);
                }
                if (lane == 0) wsum += num / den;
            }
            if (lane == 0) red[wv] = wsum;
        }
        __syncthreads();
    }

    if (tid == 0) {
        const float sval = (L > 0) ? (ws[OFF_CST + 7] + red[0] + red[1] + red[2] + red[3]) : 0.f;
        ws[OFF_S + wg] = sval;
        __threadfence();
        const int prev = atomicAdd((int*)(ws + OFF_CNT), 1);
        amLast = (prev == NBA - 1);
    }
    __syncthreads();
    if (amLast) {
        __threadfence();
        if (tid < NB) {
            const int b = tid;
            const float* s_arr = ws + OFF_S;
            const float* cst = ws + OFF_CST;
            float sum = 0.f;
            int n = 0;
            for (int aa = 0; aa < NA; ++aa) {
                if (lengths[b * NA + aa] > 0) { sum += s_arr[b * NA + aa]; ++n; }
            }
            float o = sum / ((float)n + 1e-9f);
            #pragma unroll
            for (int i = 0; i < NS; ++i)
                o = fmaf(statics[b * NS + i], cst[i], o);
            o += cst[6];
            out[b] = o;
        }
    }
}

extern "C" void kernel_launch(void* const* d_in, const int* in_sizes, int n_in,
                              void* d_out, int out_size, void* d_ws, size_t ws_size,
                              hipStream_t stream) {
    const float* data     = (const float*)d_in[0];
    // d_in[1] = time (implied by mask; unused)
    const int*   mask     = (const int*)d_in[2];
    const float* statics  = (const float*)d_in[3];
    const float* W_embed  = (const float*)d_in[4];
    const float* b_embed  = (const float*)d_in[5];
    const float* E_var    = (const float*)d_in[6];
    const float* W_static = (const float*)d_in[7];
    const float* b_static = (const float*)d_in[8];
    const float* Wq       = (const float*)d_in[9];
    const float* bq       = (const float*)d_in[10];
    const float* Wk       = (const float*)d_in[11];
    // d_in[12] = bk (uniform over t -> cancels in softmax; unused)
    const float* Wv       = (const float*)d_in[13];
    const float* bv       = (const float*)d_in[14];
    const float* Wo       = (const float*)d_in[15];
    const float* bo       = (const float*)d_in[16];
    const float* Wg       = (const float*)d_in[17];
    const float* bg       = (const float*)d_in[18];
    float* out = (float*)d_out;
    float* ws  = (float*)d_ws;

    setup_kernel<<<dim3(416), dim3(256), 0, stream>>>(Wk, Wq, bq, E_var, Wv, Wo, Wg,
                                                      bv, bo, W_static, b_static, bg, ws);
    prod_kernel<<<dim3(741), dim3(256), 0, stream>>>(data, mask, W_embed, b_embed,
                                                     E_var, Wq, ws);
    ef_kernel<<<dim3(NBA), dim3(256), 0, stream>>>(data, mask, W_embed, b_embed,
                                                   statics, ws, out);
}

// Round 8
// 185.207 us; speedup vs baseline: 1.0762x; 1.0308x over previous
//
#include <hip/hip_runtime.h>
#include <math.h>

// Problem dims
#define NB 64
#define NA 23
#define NT 128
#define ND 256
#define NAE 32
#define NS 6
#define NH 8
#define NDM 288
#define NBA (NB*NA)   // 1472

// Workspace layout (float offsets). Total ~4.67M floats = 18.7 MB.
#define OFF_PK     0           // PK[j][t] : 256*128
#define OFF_PET    32768       // peT[e][t] : 256*128
#define OFF_WKT    65536       // WkTs[j][e] = Wk[e][j]*scale : 256*256
#define OFF_VWO    131072      // VWo[h][e] : 8*288 (for evv + pem)
#define OFF_VWOP   133376      // VWoP[e][h] : 256*8 (plane layout for ef)
#define OFF_QBIAS  135424      // qbias[a][j] : 23*256
#define OFF_CST    141312      // 16 consts
#define OFF_EVV    141328      // evv[a][h] : 23*8
#define OFF_PEMT   141512      // pemT[t][h] : 128*8
#define OFF_QK     142536      // qkP[ba][e][h] : 1472*2048
#define OFF_PES    3157192     // pesT[ba][t][h] : 1472*1024
#define OFF_S      4664520     // s[ba] : 1472

#define KDIV  0.07195578415606394f    // ln(10000)/128
#define KSCALE 0.17677669529663687f   // 1/sqrt(32)

// ---------------- K1 setup: 416 blocks ----------------
__global__ __launch_bounds__(256) void setup_kernel(
    const float* __restrict__ Wk, const float* __restrict__ Wq,
    const float* __restrict__ bq, const float* __restrict__ E_var,
    const float* __restrict__ Wv, const float* __restrict__ Wo,
    const float* __restrict__ Wg, const float* __restrict__ bv,
    const float* __restrict__ bo, const float* __restrict__ W_static,
    const float* __restrict__ b_static, const float* __restrict__ bg,
    float* __restrict__ ws)
{
    const int blk = blockIdx.x, tid = threadIdx.x;
    if (blk < 128) {
        __shared__ float sm[256];
        const int t = blk;
        const int e = tid, i = e >> 1;
        const float dv = __expf(-(float)i * KDIV);
        const float ang = (float)t * dv;
        const float v = (e & 1) ? cosf(ang) : sinf(ang);
        sm[e] = v;
        ws[OFF_PET + e * NT + t] = v;
        __syncthreads();
        float acc = 0.f;
        #pragma unroll 4
        for (int e2 = 0; e2 < 256; ++e2)
            acc = fmaf(sm[e2], Wk[e2 * ND + tid], acc);
        ws[OFF_PK + tid * NT + t] = acc * KSCALE;
    } else if (blk < 384) {
        const int j = blk - 128;
        ws[OFF_WKT + j * 256 + tid] = Wk[tid * ND + j] * KSCALE;
    } else if (blk < 392) {
        const int h = blk - 384;
        __shared__ float wog[32];
        {
            const int jj = tid >> 3, sub = tid & 7;
            const int j = h * 32 + jj;
            float acc = 0.f;
            const int m0 = sub * 36;
            #pragma unroll 4
            for (int m = m0; m < m0 + 36; ++m)
                acc = fmaf(Wo[j * NDM + m], Wg[m], acc);
            acc += __shfl_down(acc, 4, 8);
            acc += __shfl_down(acc, 2, 8);
            acc += __shfl_down(acc, 1, 8);
            if (sub == 0) wog[jj] = acc;
        }
        __syncthreads();
        for (int e = tid; e < NDM; e += 256) {
            float acc = 0.f;
            #pragma unroll 8
            for (int jj = 0; jj < 32; ++jj)
                acc = fmaf(Wv[e * ND + h * 32 + jj], wog[jj], acc);
            ws[OFF_VWO + h * NDM + e] = acc;
            if (e < 256) ws[OFF_VWOP + e * 8 + h] = acc;
        }
    } else if (blk < 415) {
        const int a = blk - 392;
        float acc = bq[tid];
        #pragma unroll 8
        for (int ee = 0; ee < NAE; ++ee)
            acc = fmaf(E_var[a * NAE + ee], Wq[(256 + ee) * ND + tid], acc);
        ws[OFF_QBIAS + a * ND + tid] = acc;
    } else {
        __shared__ float sm[256];
        float acc = 0.f;
        const float* row = Wo + tid * NDM;
        for (int m = 0; m < NDM; ++m) acc = fmaf(row[m], Wg[m], acc);
        sm[tid] = acc;   // WoWg
        __syncthreads();
        const int i = tid >> 5, sub = tid & 31;
        float v = 0.f;
        if (i < 6) { for (int m = sub; m < 256; m += 32) v = fmaf(W_static[i * ND + m], Wg[NDM + m], v); }
        else if (i == 6) { for (int m = sub; m < 256; m += 32) v = fmaf(b_static[m], Wg[NDM + m], v); }
        else { for (int m = sub; m < NDM; m += 32) v = fmaf(bo[m], Wg[m], v); }
        #pragma unroll
        for (int off = 16; off > 0; off >>= 1) v += __shfl_down(v, off, 32);
        if (sub == 0) ws[OFF_CST + i] = (i == 6) ? v + bg[0] : v;
        {
            const int h = i, jj = sub;
            float u = bv[h * 32 + jj] * sm[h * 32 + jj];
            #pragma unroll
            for (int off = 16; off > 0; off >>= 1) u += __shfl_down(u, off, 32);
            if (sub == 0) ws[OFF_CST + 8 + h] = u;
        }
    }
}

// ---------------- K2 prod: 741 blocks ----------------
__global__ __launch_bounds__(256) void prod_kernel(
    const float* __restrict__ data, const int* __restrict__ lengths,
    const float* __restrict__ W_embed, const float* __restrict__ b_embed,
    const float* __restrict__ E_var, const float* __restrict__ Wq,
    float* __restrict__ ws)
{
    const int blk = blockIdx.x, tid = threadIdx.x;
    if (blk < 736) {
        const int ba0 = blk * 2;
        const int a0 = ba0 % NA, a1 = (ba0 + 1) % NA;
        const int L0 = lengths[ba0], L1 = lengths[ba0 + 1];
        __shared__ float X[2 * 128];
        __shared__ float agwS[2 * 256];
        __shared__ float qS[2 * 256];
        if (tid < 128) {
            X[tid]       = data[ba0 * NT + tid];
            X[128 + tid] = data[(ba0 + 1) * NT + tid];
        }
        __syncthreads();
        {
            const int e = tid, ii = e >> 1;
            const float dv = __expf(-(float)ii * KDIV);
            const float hd = 0.5f * dv;
            const float ish = 1.f / sinf(hd);
            #pragma unroll
            for (int i = 0; i < 2; ++i) {
                const int a = i ? a1 : a0;
                const int Li = i ? L1 : L0;
                const float We = W_embed[a * ND + e];
                const float be = b_embed[a * ND + e];
                float acc = 0.f;
                #pragma unroll 4
                for (int t = 0; t < Li; ++t)
                    acc += fmaxf(fmaf(X[i * 128 + t], We, be), 0.f);
                float r = 0.f;
                if (Li > 0) {
                    const float s1 = sinf((float)Li * hd);
                    const float a2 = (float)(Li - 1) * hd;
                    const float num = (e & 1) ? cosf(a2) : sinf(a2);
                    r = (acc + num * s1 * ish) / (float)Li;
                }
                agwS[i * 256 + e] = r;
            }
        }
        __syncthreads();
        {
            const int j = tid;
            float acc0 = ws[OFF_QBIAS + a0 * ND + j];
            float acc1 = ws[OFF_QBIAS + a1 * ND + j];
            #pragma unroll 8
            for (int f = 0; f < 256; ++f) {
                const float w = Wq[f * ND + j];
                acc0 = fmaf(agwS[f], w, acc0);
                acc1 = fmaf(agwS[256 + f], w, acc1);
            }
            qS[j] = acc0;
            qS[256 + j] = acc1;
        }
        __syncthreads();
        {
            const int e = tid;
            float q0[8], q1[8];
            for (int h = 0; h < 8; ++h) {
                float acc0 = 0.f, acc1 = 0.f;
                const float* wkp = ws + OFF_WKT + (h * 32) * 256 + e;
                #pragma unroll 8
                for (int j = 0; j < 32; ++j) {
                    const float w = wkp[j * 256];
                    acc0 = fmaf(qS[h * 32 + j], w, acc0);
                    acc1 = fmaf(qS[256 + h * 32 + j], w, acc1);
                }
                q0[h] = acc0; q1[h] = acc1;
            }
            float4* o0 = (float4*)(ws + OFF_QK + (size_t)ba0 * 2048 + e * 8);
            float4* o1 = (float4*)(ws + OFF_QK + (size_t)(ba0 + 1) * 2048 + e * 8);
            o0[0] = make_float4(q0[0], q0[1], q0[2], q0[3]);
            o0[1] = make_float4(q0[4], q0[5], q0[6], q0[7]);
            o1[0] = make_float4(q1[0], q1[1], q1[2], q1[3]);
            o1[1] = make_float4(q1[4], q1[5], q1[6], q1[7]);
        }
        {
            const int t = tid & 127, hg = tid >> 7;
            float p0[4], p1[4];
            #pragma unroll
            for (int p = 0; p < 4; ++p) { p0[p] = 0.f; p1[p] = 0.f; }
            #pragma unroll
            for (int p = 0; p < 4; ++p) {
                const int h = hg * 4 + p;
                const float* pkp = ws + OFF_PK + (h * 32) * 128 + t;
                #pragma unroll 4
                for (int j = 0; j < 32; ++j) {
                    const float pk = pkp[j * 128];
                    p0[p] = fmaf(qS[h * 32 + j], pk, p0[p]);
                    p1[p] = fmaf(qS[256 + h * 32 + j], pk, p1[p]);
                }
            }
            if (t < L0)
                ((float4*)(ws + OFF_PES + (size_t)ba0 * 1024 + t * 8))[hg] =
                    make_float4(p0[0], p0[1], p0[2], p0[3]);
            if (t < L1)
                ((float4*)(ws + OFF_PES + (size_t)(ba0 + 1) * 1024 + t * 8))[hg] =
                    make_float4(p1[0], p1[1], p1[2], p1[3]);
        }
    } else if (blk < 740) {
        const int h = (blk - 736) * 2 + (tid >> 7);
        const int t = tid & 127;
        float acc = 0.f;
        #pragma unroll 4
        for (int e = 0; e < 256; ++e)
            acc = fmaf(ws[OFF_PET + e * NT + t], ws[OFF_VWO + h * NDM + e], acc);
        ws[OFF_PEMT + t * 8 + h] = acc;
    } else {
        if (tid < 184) {
            const int a = tid >> 3, h = tid & 7;
            float acc = 0.f;
            #pragma unroll 8
            for (int ee = 0; ee < NAE; ++ee)
                acc = fmaf(E_var[a * NAE + ee], ws[OFF_VWO + h * NDM + 256 + ee], acc);
            ws[OFF_EVV + tid] = acc;
        }
    }
}

// ---------------- K3 ef: 1472 blocks (no atomic ticket; prefetched pes/pem) ----------------
__global__ __launch_bounds__(256) void ef_kernel(
    const float* __restrict__ data, const int* __restrict__ lengths,
    const float* __restrict__ W_embed, const float* __restrict__ b_embed,
    float* __restrict__ ws)
{
    const int wg = blockIdx.x, tid = threadIdx.x;
    const int a = wg % NA;
    const int L = lengths[wg];

    __shared__ __align__(16) float combo[4096]; // planes [qk03|qk47|vw03|vw47][e]; reused as sc/mvb/partials
    __shared__ float xs[128];
    __shared__ float2 Wb[256];
    __shared__ float red[4];

    if (L == 0) { if (tid == 0) ws[OFF_S + wg] = 0.f; return; }

    // softmax constants for this wave's 2 heads — issued early
    const int wv = tid >> 6;
    const float vb0 = ws[OFF_EVV + a * 8 + wv * 2]     + ws[OFF_CST + 8 + wv * 2];
    const float vb1 = ws[OFF_EVV + a * 8 + wv * 2 + 1] + ws[OFF_CST + 8 + wv * 2 + 1];

    if (tid < 128) xs[tid] = data[wg * NT + tid];
    Wb[tid] = make_float2(W_embed[a * ND + tid], b_embed[a * ND + tid]);
    {
        float4* cb4w = (float4*)combo;
        const float4* qkp = (const float4*)(ws + OFF_QK + (size_t)wg * 2048);
        const float4* vwp = (const float4*)(ws + OFF_VWOP);
        cb4w[tid]       = qkp[tid * 2];
        cb4w[256 + tid] = qkp[tid * 2 + 1];
        cb4w[512 + tid] = vwp[tid * 2];
        cb4w[768 + tid] = vwp[tid * 2 + 1];
    }
    __syncthreads();

    const int t = tid & 127, half = tid >> 7;
    const int tlo = tid & 64;            // this wave's t-range base (0 or 64)
    const bool act = (L > tlo);          // wave-uniform skip

    // Prefetch pes/pem now — latency overlaps the hot loop below.
    float4 ps0 = make_float4(0,0,0,0), ps1 = ps0, pm0 = ps0, pm1 = ps0;
    if (half == 0) {
        const float4* pes = (const float4*)(ws + OFF_PES + (size_t)wg * 1024 + t * 8);
        const float4* pem = (const float4*)(ws + OFF_PEMT + t * 8);
        ps0 = pes[0]; ps1 = pes[1];
        pm0 = pem[0]; pm1 = pem[1];
    }

    float accS[8], accM[8];
    #pragma unroll
    for (int h = 0; h < 8; ++h) { accS[h] = 0.f; accM[h] = 0.f; }
    if (act) {
        const float xt = xs[t];
        const int ebase = half * 128;
        const float4* cb4 = (const float4*)combo;
        #pragma unroll 2
        for (int ee = 0; ee < 128; ++ee) {
            const float2 wb = Wb[ebase + ee];
            const float m = fmaxf(fmaf(xt, wb.x, wb.y), 0.f);
            const float4 c0 = cb4[ebase + ee];
            const float4 c1 = cb4[256 + ebase + ee];
            const float4 c2 = cb4[512 + ebase + ee];
            const float4 c3 = cb4[768 + ebase + ee];
            accS[0] = fmaf(m, c0.x, accS[0]); accS[1] = fmaf(m, c0.y, accS[1]);
            accS[2] = fmaf(m, c0.z, accS[2]); accS[3] = fmaf(m, c0.w, accS[3]);
            accS[4] = fmaf(m, c1.x, accS[4]); accS[5] = fmaf(m, c1.y, accS[5]);
            accS[6] = fmaf(m, c1.z, accS[6]); accS[7] = fmaf(m, c1.w, accS[7]);
            accM[0] = fmaf(m, c2.x, accM[0]); accM[1] = fmaf(m, c2.y, accM[1]);
            accM[2] = fmaf(m, c2.z, accM[2]); accM[3] = fmaf(m, c2.w, accM[3]);
            accM[4] = fmaf(m, c3.x, accM[4]); accM[5] = fmaf(m, c3.y, accM[5]);
            accM[6] = fmaf(m, c3.z, accM[6]); accM[7] = fmaf(m, c3.w, accM[7]);
        }
    }
    __syncthreads();   // all combo reads done -> reuse region
    float* sc  = combo;
    float* mvb = combo + 1024;
    float* scP = combo + 2048;
    float* mvP = combo + 3072;
    if (half == 1 && act) {
        #pragma unroll
        for (int h = 0; h < 8; ++h) { scP[h * 128 + t] = accS[h]; mvP[h * 128 + t] = accM[h]; }
    }
    __syncthreads();
    if (half == 0 && act) {
        const float psA[8] = {ps0.x, ps0.y, ps0.z, ps0.w, ps1.x, ps1.y, ps1.z, ps1.w};
        const float pmA[8] = {pm0.x, pm0.y, pm0.z, pm0.w, pm1.x, pm1.y, pm1.z, pm1.w};
        #pragma unroll
        for (int h = 0; h < 8; ++h) {
            sc[h * 128 + t]  = accS[h] + scP[h * 128 + t] + psA[h];
            mvb[h * 128 + t] = accM[h] + mvP[h * 128 + t] + pmA[h];
        }
    }
    __syncthreads();

    // per-head softmax over t<L; s_h = sum_t p*(mv+vb)
    {
        const int lane = tid & 63;
        float wsum = 0.f;
        #pragma unroll
        for (int hh = 0; hh < 2; ++hh) {
            const int h = wv * 2 + hh;
            const float vbv = hh ? vb1 : vb0;
            float s1 = (lane < L) ? sc[h * 128 + lane] : -3e38f;
            float s2 = (lane + 64 < L) ? sc[h * 128 + 64 + lane] : -3e38f;
            float mx = fmaxf(s1, s2);
            #pragma unroll
            for (int off = 32; off > 0; off >>= 1)
                mx = fmaxf(mx, __shfl_down(mx, off, 64));
            mx = __shfl(mx, 0, 64);
            float e1 = (lane < L) ? __expf(s1 - mx) : 0.f;
            float e2 = (lane + 64 < L) ? __expf(s2 - mx) : 0.f;
            float num = (lane < L) ? e1 * (mvb[h * 128 + lane] + vbv) : 0.f;
            if (lane + 64 < L) num = fmaf(e2, mvb[h * 128 + 64 + lane] + vbv, num);
            float den = e1 + e2;
            #pragma unroll
            for (int off = 32; off > 0; off >>= 1) {
                num += __shfl_down(num, off, 64);
                den += __shfl_down(den, off, 64);
            }
            if (lane == 0) wsum += num / den;
        }
        if (lane == 0) red[wv] = wsum;
    }
    __syncthreads();
    if (tid == 0)
        ws[OFF_S + wg] = ws[OFF_CST + 7] + red[0] + red[1] + red[2] + red[3];
}

// ---------------- K4 final: 1 block ----------------
__global__ __launch_bounds__(64) void final_kernel(
    const float* __restrict__ statics, const int* __restrict__ lengths,
    const float* __restrict__ ws, float* __restrict__ out)
{
    const int b = threadIdx.x;
    const float* s_arr = ws + OFF_S;
    const float* cst = ws + OFF_CST;
    float sum = 0.f;
    int n = 0;
    for (int a = 0; a < NA; ++a) {
        if (lengths[b * NA + a] > 0) { sum += s_arr[b * NA + a]; ++n; }
    }
    float o = sum / ((float)n + 1e-9f);
    #pragma unroll
    for (int i = 0; i < NS; ++i)
        o = fmaf(statics[b * NS + i], cst[i], o);
    o += cst[6];
    out[b] = o;
}

extern "C" void kernel_launch(void* const* d_in, const int* in_sizes, int n_in,
                              void* d_out, int out_size, void* d_ws, size_t ws_size,
                              hipStream_t stream) {
    const float* data     = (const float*)d_in[0];
    // d_in[1] = time (implied by mask; unused)
    const int*   mask     = (const int*)d_in[2];
    const float* statics  = (const float*)d_in[3];
    const float* W_embed  = (const float*)d_in[4];
    const float* b_embed  = (const float*)d_in[5];
    const float* E_var    = (const float*)d_in[6];
    const float* W_static = (const float*)d_in[7];
    const float* b_static = (const float*)d_in[8];
    const float* Wq       = (const float*)d_in[9];
    const float* bq       = (const float*)d_in[10];
    const float* Wk       = (const float*)d_in[11];
    // d_in[12] = bk (uniform over t -> cancels in softmax; unused)
    const float* Wv       = (const float*)d_in[13];
    const float* bv       = (const float*)d_in[14];
    const float* Wo       = (const float*)d_in[15];
    const float* bo       = (const float*)d_in[16];
    const float* Wg       = (const float*)d_in[17];
    const float* bg       = (const float*)d_in[18];
    float* out = (float*)d_out;
    float* ws  = (float*)d_ws;

    setup_kernel<<<dim3(416), dim3(256), 0, stream>>>(Wk, Wq, bq, E_var, Wv, Wo, Wg,
                                                      bv, bo, W_static, b_static, bg, ws);
    prod_kernel<<<dim3(741), dim3(256), 0, stream>>>(data, mask, W_embed, b_embed,
                                                     E_var, Wq, ws);
    ef_kernel<<<dim3(NBA), dim3(256), 0, stream>>>(data, mask, W_embed, b_embed, ws);
    final_kernel<<<dim3(1), dim3(64), 0, stream>>>(statics, mask, ws, out);
}